// Round 18
// baseline (370.521 us; speedup 1.0000x reference)
//
#include <hip/hip_runtime.h>
#include <cstdint>

// B=8, S=16, N=1024, F=16, H=128, E=32768, L=4, BN=8192
#define EPS 1e-5f

typedef unsigned short ushort_t;
typedef __bf16 bf16x8 __attribute__((ext_vector_type(8)));
typedef float f32x4 __attribute__((ext_vector_type(4)));

#define GLD16(gp, lp) __builtin_amdgcn_global_load_lds( \
    (const __attribute__((address_space(1))) void*)(gp), \
    (__attribute__((address_space(3))) void*)(lp), 16, 0, 0)

__device__ __forceinline__ float sigm(float x) { return 1.f / (1.f + expf(-x)); }
__device__ __forceinline__ unsigned short f2bf(float f) {
    unsigned int u = __builtin_bit_cast(unsigned int, f);
    return (unsigned short)((u + 0x7fffu + ((u >> 16) & 1u)) >> 16);
}
__device__ __forceinline__ float bf2f(unsigned short s) {
    unsigned int u = ((unsigned int)s) << 16;
    return __builtin_bit_cast(float, u);
}
__device__ __forceinline__ float sigm_fast(float x) {
    float t = __builtin_amdgcn_exp2f(-1.44269504f * x);
    return __builtin_amdgcn_rcpf(1.f + t);
}
__device__ __forceinline__ float tanh_fast(float x) {
    float xc = fminf(fmaxf(x, -15.f), 15.f);
    float t = __builtin_amdgcn_exp2f(-2.88539008f * xc);
    return (1.f - t) * __builtin_amdgcn_rcpf(1.f + t);
}

// ---------------- edge attention + degree accumulate
__global__ __launch_bounds__(256) void edge_att_deg(const float* __restrict__ ef,
                                                    const float* __restrict__ we1,
                                                    const float* __restrict__ be1,
                                                    const float* __restrict__ we2,
                                                    const float* __restrict__ be2,
                                                    const float* __restrict__ ewin,
                                                    const int* __restrict__ dst,
                                                    float* __restrict__ ew,
                                                    float* __restrict__ deg) {
    int e = blockIdx.x * blockDim.x + threadIdx.x;
    if (e >= 32768) return;
    float x = ef[e];
    float acc = 0.f;
    for (int h = 0; h < 128; ++h) {
        float v = fmaxf(x * we1[h] + be1[h], 0.f);
        acc += v * we2[h];
    }
    float wv = ewin[e] * sigm(acc + be2[0]);
    ew[e] = wv;
    atomicAdd(&deg[dst[e]], wv);
}
__global__ __launch_bounds__(256) void make_dis(float* __restrict__ deg) {
    int i = blockIdx.x * blockDim.x + threadIdx.x;
    if (i < 1024) { float d = deg[i] + 1.0f; deg[i] = (d > 0.f) ? rsqrtf(d) : 0.f; }
}
__global__ __launch_bounds__(256) void scatterA(const int* __restrict__ src,
                                                const int* __restrict__ dst,
                                                const float* __restrict__ ew,
                                                const float* __restrict__ dis,
                                                float* __restrict__ A) {
    int e = blockIdx.x * blockDim.x + threadIdx.x;
    if (e >= 32768) return;
    int s = src[e], d = dst[e];
    atomicAdd(&A[d * 1024 + s], dis[s] * ew[e] * dis[d]);
}

// ---------------- converters
__global__ __launch_bounds__(256) void convF2B(const float* __restrict__ s,
                                               ushort_t* __restrict__ d, int n) {
    int i = blockIdx.x * blockDim.x + threadIdx.x;
    if (i < n) d[i] = f2bf(s[i]);
}
// merged conversions (64-col gate layout: col' = (h>>4)*64 + gate*16 + (h&15))
__global__ __launch_bounds__(256) void conv_all(const float* __restrict__ gcnw,
                                                const float* __restrict__ wih,
                                                const float* __restrict__ whh,
                                                const float* __restrict__ bih,
                                                const float* __restrict__ bhh,
                                                ushort_t* __restrict__ gcnwT,
                                                ushort_t* __restrict__ wgi,
                                                ushort_t* __restrict__ wgh,
                                                float* __restrict__ bsg) {
    int i = blockIdx.x * 256 + threadIdx.x;
    if (i < 65536) {                       // gcnw [l][in][out] -> [l][out][in] bf16
        int l = i >> 14, rem = i & 16383, in = rem >> 7, outc = rem & 127;
        gcnwT[l * 16384 + outc * 128 + in] = f2bf(gcnw[i]);
        return;
    }
    int j = i - 65536;
    if (j < 131072) {
        int l = j >> 16, rem = j & 65535, c = rem >> 7, kx = rem & 127;
        int g = (c >> 4) & 3, h = (c >> 6) * 16 + (c & 15);
        int src = (l * 512 + g * 128 + h) * 128 + kx;
        wgi[j] = f2bf(wih[src]);
        wgh[j] = f2bf(whh[src]);
        return;
    }
    int b = j - 131072;
    if (b < 1024) {
        int l = b >> 9, c = b & 511;
        int g = (c >> 4) & 3, h = (c >> 6) * 16 + (c & 15);
        int src = l * 512 + g * 128 + h;
        bsg[b] = bih[src] + bhh[src];
    }
}

// ---------------- input projection + LN + ReLU, wave-per-row (barrier-free)
__global__ __launch_bounds__(256) void in_proj_ln(const float* __restrict__ x,
                                                  const float* __restrict__ w,
                                                  const float* __restrict__ bias,
                                                  const float* __restrict__ g,
                                                  const float* __restrict__ be,
                                                  ushort_t* __restrict__ hA,
                                                  ushort_t* __restrict__ hB) {
    int row = blockIdx.x * 4 + (threadIdx.x >> 6);   // < 23552
    int lane = threadIdx.x & 63;
    int k = row >> 10, n = row & 1023;
    float xv = x[(int64_t)row * 16 + (lane & 15)];
    float a0 = bias[lane], a1 = bias[lane + 64];
#pragma unroll
    for (int f = 0; f < 16; ++f) {
        float xf = __shfl(xv, f, 16);
        a0 += xf * w[f * 128 + lane];
        a1 += xf * w[f * 128 + lane + 64];
    }
    float s = a0 + a1;
#pragma unroll
    for (int off = 1; off < 64; off <<= 1) s += __shfl_xor(s, off, 64);
    float mu = s * (1.f / 128.f);
    float d0 = a0 - mu, d1 = a1 - mu;
    float vs = d0 * d0 + d1 * d1;
#pragma unroll
    for (int off = 1; off < 64; off <<= 1) vs += __shfl_xor(vs, off, 64);
    float rstd = rsqrtf(vs * (1.f / 128.f) + EPS);
    float v0 = fmaxf(d0 * rstd * g[lane] + be[lane], 0.f);
    float v1 = fmaxf(d1 * rstd * g[lane + 64] + be[lane + 64], 0.f);
    int64_t idx = ((int64_t)k * 1024 + n) * 128 + lane;
    ushort_t b0 = f2bf(v0), b1v = f2bf(v1);
    if (k < 16) { hA[idx] = b0; hA[idx + 64] = b1v; }
    hB[idx] = b0; hB[idx + 64] = b1v;
}

// ---------------- feature GEMM from hA, transposed output hwT[t][col][bn]
__global__ __launch_bounds__(256) void gemm_feat_t(const ushort_t* __restrict__ hA,
                                                   const ushort_t* __restrict__ Wt,
                                                   ushort_t* __restrict__ hwT) {
    __shared__ __align__(16) char AsB[32768];
    __shared__ __align__(16) char BsB[32768];
    const int tid = threadIdx.x, lane = tid & 63, wid = tid >> 6;
    const int wr = wid >> 1, wc = wid & 1, q = lane >> 4, l15 = lane & 15;
    const int t = blockIdx.y;
    const int row0 = blockIdx.x * 128;
    const ushort_t* Ap = hA + ((int64_t)t * 1024 + row0) * 128;
    f32x4 acc[4][4];
#pragma unroll
    for (int m = 0; m < 4; ++m)
#pragma unroll
        for (int n = 0; n < 4; ++n) acc[m][n] = f32x4{0.f, 0.f, 0.f, 0.f};
#pragma unroll
    for (int i = 0; i < 8; ++i) {
        int id = i * 256 + tid; int r = id >> 4, sg = id & 15;
        uint4 va = *(const uint4*)(Ap + r * 128 + sg * 8);
        *(uint4*)(AsB + r * 256 + ((sg * 16) ^ ((r & 7) << 4))) = va;
        uint4 vb = *(const uint4*)(Wt + r * 128 + sg * 8);
        *(uint4*)(BsB + r * 256 + ((sg * 16) ^ ((r & 7) << 4))) = vb;
    }
    __syncthreads();
#pragma unroll
    for (int kk = 0; kk < 4; ++kk) {
        bf16x8 af[4], bfr[4];
#pragma unroll
        for (int m = 0; m < 4; ++m) {
            int row = wr * 64 + m * 16 + l15;
            af[m] = __builtin_bit_cast(bf16x8,
                *(const uint4*)(AsB + row * 256 + ((kk * 64 + q * 16) ^ ((row & 7) << 4))));
        }
#pragma unroll
        for (int n = 0; n < 4; ++n) {
            int col = wc * 64 + n * 16 + l15;
            bfr[n] = __builtin_bit_cast(bf16x8,
                *(const uint4*)(BsB + col * 256 + ((kk * 64 + q * 16) ^ ((col & 7) << 4))));
        }
#pragma unroll
        for (int m = 0; m < 4; ++m)
#pragma unroll
            for (int n = 0; n < 4; ++n)
                acc[m][n] = __builtin_amdgcn_mfma_f32_16x16x32_bf16(af[m], bfr[n], acc[m][n], 0, 0, 0);
    }
#pragma unroll
    for (int m = 0; m < 4; ++m) {
        int bn = row0 + wr * 64 + m * 16 + q * 4;
#pragma unroll
        for (int n = 0; n < 4; ++n) {
            int col = wc * 64 + n * 16 + l15;
            ushort4 u;
            u.x = f2bf(acc[m][n][0]); u.y = f2bf(acc[m][n][1]);
            u.z = f2bf(acc[m][n][2]); u.w = f2bf(acc[m][n][3]);
            *(ushort4*)(hwT + ((int64_t)t * 128 + col) * 1024 + bn) = u;
        }
    }
}

// ---------------- merged GCN layer: feat GEMM + adjacency GEMM in registers + combine.
__global__ __launch_bounds__(256) void gcn_layer(ushort_t* __restrict__ hA,
                                                 ushort_t* __restrict__ hB,
                                                 const ushort_t* __restrict__ Wt,
                                                 const ushort_t* __restrict__ Abf,
                                                 const ushort_t* __restrict__ hwT,
                                                 const float* __restrict__ dis,
                                                 const float* __restrict__ gcnb,
                                                 const float* __restrict__ bng,
                                                 const float* __restrict__ bnb) {
    __shared__ __align__(16) char AsB[16384];
    __shared__ __align__(16) char BsB[32768];
    const int tid = threadIdx.x, lane = tid & 63, wid = tid >> 6;
    const int wr = wid >> 1, wc = wid & 1, q = lane >> 4, l15 = lane & 15;
    const int bx = blockIdx.x;
    const bool adj = bx < 256;
    const int lb = adj ? bx : bx - 256;
    const int tt = lb >> 4;
    const int n0 = (lb & 15) * 64;
    ushort_t* Ap = (adj ? hA : hB) + ((int64_t)tt * 1024 + n0) * 128;

#pragma unroll
    for (int i = 0; i < 4; ++i) {
        int id = i * 256 + tid; int r = id >> 4, sg = id & 15;
        uint4 va = *(const uint4*)(Ap + r * 128 + sg * 8);
        *(uint4*)(AsB + r * 256 + ((sg * 16) ^ ((r & 7) << 4))) = va;
    }
#pragma unroll
    for (int i = 0; i < 8; ++i) {
        int id = i * 256 + tid; int r = id >> 4, sg = id & 15;
        uint4 vb = *(const uint4*)(Wt + r * 128 + sg * 8);
        *(uint4*)(BsB + r * 256 + ((sg * 16) ^ ((r & 7) << 4))) = vb;
    }
    __syncthreads();

    f32x4 accF[2][4];
#pragma unroll
    for (int m = 0; m < 2; ++m)
#pragma unroll
        for (int n = 0; n < 4; ++n) accF[m][n] = f32x4{0.f, 0.f, 0.f, 0.f};
#pragma unroll
    for (int kk = 0; kk < 4; ++kk) {
        bf16x8 af[2], bfr[4];
#pragma unroll
        for (int m = 0; m < 2; ++m) {
            int row = wr * 32 + m * 16 + l15;
            af[m] = __builtin_bit_cast(bf16x8,
                *(const uint4*)(AsB + row * 256 + ((kk * 64 + q * 16) ^ ((row & 7) << 4))));
        }
#pragma unroll
        for (int n = 0; n < 4; ++n) {
            int col = wc * 64 + n * 16 + l15;
            bfr[n] = __builtin_bit_cast(bf16x8,
                *(const uint4*)(BsB + col * 256 + ((kk * 64 + q * 16) ^ ((col & 7) << 4))));
        }
#pragma unroll
        for (int m = 0; m < 2; ++m)
#pragma unroll
            for (int n = 0; n < 4; ++n)
                accF[m][n] = __builtin_amdgcn_mfma_f32_16x16x32_bf16(af[m], bfr[n], accF[m][n], 0, 0, 0);
    }

    f32x4 accA[2][4];
#pragma unroll
    for (int m = 0; m < 2; ++m)
#pragma unroll
        for (int n = 0; n < 4; ++n) accA[m][n] = f32x4{0.f, 0.f, 0.f, 0.f};
    if (adj) {
        const int rl8 = lane >> 3;
        const int sgg = (lane & 7) ^ rl8;
        for (int k0 = 0; k0 < 1024; k0 += 64) {
            __syncthreads();
#pragma unroll
            for (int i = 0; i < 2; ++i) {
                int r = i * 32 + wid * 8 + rl8;
                GLD16(Abf + (int64_t)(n0 + r) * 1024 + k0 + sgg * 8,
                      BsB + (i * 32 + wid * 8) * 128);
            }
#pragma unroll
            for (int i = 0; i < 4; ++i) {
                int r = i * 32 + wid * 8 + rl8;
                GLD16(hwT + (int64_t)tt * 131072 + (int64_t)r * 1024 + k0 + sgg * 8,
                      BsB + 8192 + (i * 32 + wid * 8) * 128);
            }
            __syncthreads();
#pragma unroll
            for (int kk = 0; kk < 2; ++kk) {
                bf16x8 af2[2], bf2[4];
#pragma unroll
                for (int m = 0; m < 2; ++m) {
                    int row = wr * 32 + m * 16 + l15;
                    af2[m] = __builtin_bit_cast(bf16x8,
                        *(const uint4*)(BsB + row * 128 + ((kk * 64 + q * 16) ^ ((row & 7) << 4))));
                }
#pragma unroll
                for (int n = 0; n < 4; ++n) {
                    int col = wc * 64 + n * 16 + l15;
                    bf2[n] = __builtin_bit_cast(bf16x8,
                        *(const uint4*)(BsB + 8192 + col * 128 + ((kk * 64 + q * 16) ^ ((col & 7) << 4))));
                }
#pragma unroll
                for (int m = 0; m < 2; ++m)
#pragma unroll
                    for (int n = 0; n < 4; ++n)
                        accA[m][n] = __builtin_amdgcn_mfma_f32_16x16x32_bf16(af2[m], bf2[n], accA[m][n], 0, 0, 0);
            }
        }
    }
    __syncthreads();

    const float rs = rsqrtf(1.f + EPS);
#pragma unroll
    for (int n = 0; n < 4; ++n) {
        int col = wc * 64 + n * 16 + l15;
        float gb = gcnb[col], sc = bng[col] * rs, bb = bnb[col];
        int seg16 = (col >> 3) * 16, wb = (col & 7) * 2;
#pragma unroll
        for (int m = 0; m < 2; ++m) {
            int rl0 = wr * 32 + m * 16 + q * 4;
#pragma unroll
            for (int e = 0; e < 4; ++e) {
                int rl = rl0 + e;
                float sl = 1.f, ad = 0.f;
                if (adj) { float dv = dis[n0 + rl]; sl = dv * dv; ad = accA[m][n][e]; }
                float mv = sl * accF[m][n][e] + gb + ad;
                ushort_t rbv = *(const ushort_t*)(AsB + rl * 256 + (seg16 ^ ((rl & 7) << 4)) + wb);
                float v = fmaxf(mv * sc + bb, 0.f) + bf2f(rbv);
                *(ushort_t*)(BsB + rl * 256 + (seg16 ^ ((rl & 7) << 4)) + wb) = f2bf(v);
            }
        }
    }
    __syncthreads();
#pragma unroll
    for (int i = 0; i < 4; ++i) {
        int id = i * 256 + tid; int r = id >> 4, sg = id & 15;
        uint4 v = *(const uint4*)(BsB + r * 256 + ((sg * 16) ^ ((r & 7) << 4)));
        *(uint4*)(Ap + r * 128 + sg * 8) = v;
    }
}

// ---------------- LSTM layer: 64 ROWS PER WAVE (m=4), 128 blocks x 512 threads.
// (fix vs round 17: zero the FULL 16KB of Hs slot 0, not just 8KB)
template <int MODE>
__global__ __launch_bounds__(512, 2) void lstm_layer(
    const ushort_t* __restrict__ hA, const ushort_t* __restrict__ hB,
    const ushort_t* __restrict__ X,
    const ushort_t* __restrict__ Wi, const ushort_t* __restrict__ Wh,
    const float* __restrict__ bs,
    ushort_t* __restrict__ Y,
    const float* __restrict__ w1, const float* __restrict__ b1,
    const float* __restrict__ lg, const float* __restrict__ lb,
    const float* __restrict__ w2, const float* __restrict__ b2,
    float* __restrict__ out) {
    __shared__ __align__(16) char Xs[32768];   // 2 slots x 64 rows x 256B
    __shared__ __align__(16) char Hs[32768];   // 2 slots
    __shared__ __align__(16) char W1s[32768];
    const int tid = threadIdx.x, lane = tid & 63, w = tid >> 6;
    const int q = lane >> 4, l15 = lane & 15;
    const int row0 = blockIdx.x * 64;
    const int r = tid >> 4, sg = tid & 15;     // staging: 32 rows per pass
    const int bb = row0 >> 10, n0 = row0 & 1023;

    *(uint4*)(Hs + tid * 16) = uint4{0, 0, 0, 0};           // zero slot 0 rows 0-31
    *(uint4*)(Hs + 8192 + tid * 16) = uint4{0, 0, 0, 0};    // zero slot 0 rows 32-63
    if constexpr (MODE == 1) {
#pragma unroll
        for (int i = 0; i < 4; ++i)
            *(uint4*)(W1s + (i * 512 + tid) * 16) =
                *(const uint4*)((const char*)w1 + (i * 512 + tid) * 16);
    }
    bf16x8 wi[4][4], wh[4][4];
#pragma unroll
    for (int n = 0; n < 4; ++n)
#pragma unroll
        for (int kk = 0; kk < 4; ++kk) {
            int col = w * 64 + n * 16 + l15;
            wi[n][kk] = __builtin_bit_cast(bf16x8, *(const uint4*)(Wi + col * 128 + kk * 32 + q * 8));
            wh[n][kk] = __builtin_bit_cast(bf16x8, *(const uint4*)(Wh + col * 128 + kk * 32 + q * 8));
        }
    const int cb = w * 64 + l15;
    const float bi = bs[cb], bf = bs[cb + 16], bg = bs[cb + 32], bo = bs[cb + 48];
    const int k = w * 16 + l15;
    float c[4][4] = {};

    auto xsrc = [&](int t) -> const ushort_t* {
        if constexpr (MODE == 0)
            return (bb == 0) ? hA + ((int64_t)t * 1024 + n0) * 128
                             : hB + ((int64_t)(t + bb) * 1024 + n0) * 128;
        else
            return X + ((int64_t)t * 8192 + row0) * 128;
    };

#pragma unroll
    for (int i = 0; i < 2; ++i) {
        int rr = i * 32 + r;
        uint4 x0 = *(const uint4*)(xsrc(0) + rr * 128 + sg * 8);
        *(uint4*)(Xs + rr * 256 + ((sg * 16) ^ ((rr & 7) << 4))) = x0;
    }
    __syncthreads();

    for (int t = 0; t < 16; ++t) {
        const int p = (t & 1) * 16384, pn = ((t + 1) & 1) * 16384;
        uint4 xn0, xn1;
        if (t < 15) {
            xn0 = *(const uint4*)(xsrc(t + 1) + r * 128 + sg * 8);
            xn1 = *(const uint4*)(xsrc(t + 1) + (32 + r) * 128 + sg * 8);
        }

        f32x4 acc[4][4];
#pragma unroll
        for (int m = 0; m < 4; ++m)
#pragma unroll
            for (int n = 0; n < 4; ++n) acc[m][n] = f32x4{0.f, 0.f, 0.f, 0.f};
#pragma unroll
        for (int kk = 0; kk < 4; ++kk) {
            bf16x8 ax[4], ah[4];
#pragma unroll
            for (int m = 0; m < 4; ++m) {
                int rw = m * 16 + l15;
                int off = rw * 256 + ((kk * 64 + q * 16) ^ ((rw & 7) << 4));
                ax[m] = __builtin_bit_cast(bf16x8, *(const uint4*)(Xs + p + off));
                ah[m] = __builtin_bit_cast(bf16x8, *(const uint4*)(Hs + p + off));
            }
#pragma unroll
            for (int n = 0; n < 4; ++n)
#pragma unroll
                for (int m = 0; m < 4; ++m) {
                    acc[m][n] = __builtin_amdgcn_mfma_f32_16x16x32_bf16(ax[m], wi[n][kk], acc[m][n], 0, 0, 0);
                    acc[m][n] = __builtin_amdgcn_mfma_f32_16x16x32_bf16(ah[m], wh[n][kk], acc[m][n], 0, 0, 0);
                }
        }
        // cell -> write h to OTHER slot (no WAR with current-step readers)
#pragma unroll
        for (int m = 0; m < 4; ++m)
#pragma unroll
            for (int e = 0; e < 4; ++e) {
                float ig = sigm_fast(acc[m][0][e] + bi);
                float fg = sigm_fast(acc[m][1][e] + bf);
                float gg = tanh_fast(acc[m][2][e] + bg);
                float og = sigm_fast(acc[m][3][e] + bo);
                float cn = fg * c[m][e] + ig * gg;
                c[m][e] = cn;
                float hn = og * tanh_fast(cn);
                int rw = m * 16 + q * 4 + e;
                int byte = rw * 256 + ((((k >> 3) * 16) ^ ((rw & 7) << 4)) | ((k & 7) * 2));
                *(ushort_t*)(Hs + pn + byte) = f2bf(hn);
            }
        if (t < 15) {
            *(uint4*)(Xs + pn + r * 256 + ((sg * 16) ^ ((r & 7) << 4))) = xn0;
            int rr = 32 + r;
            *(uint4*)(Xs + pn + rr * 256 + ((sg * 16) ^ ((rr & 7) << 4))) = xn1;
        }
        __syncthreads();   // single barrier: slot t+1 (X and H) complete

        if constexpr (MODE == 0) {
#pragma unroll
            for (int i = 0; i < 2; ++i) {
                int rr = i * 32 + r;
                uint4 v = *(const uint4*)(Hs + pn + rr * 256 + ((sg * 16) ^ ((rr & 7) << 4)));
                *(uint4*)(Y + ((int64_t)t * 8192 + row0 + rr) * 128 + sg * 8) = v;
            }
        }
    }

    if constexpr (MODE == 1) {
        // final h2 in Hs slot 0; head over 64 rows (2 passes of 32)
#pragma unroll
        for (int i = 0; i < 2; ++i) {
            int rr = i * 32 + r;
            float accj[4] = {b1[sg * 4 + 0], b1[sg * 4 + 1], b1[sg * 4 + 2], b1[sg * 4 + 3]};
#pragma unroll
            for (int kb = 0; kb < 16; ++kb) {
                uint4 hv = *(const uint4*)(Hs + rr * 256 + ((kb * 16) ^ ((rr & 7) << 4)));
                const ushort_t* hp = (const ushort_t*)&hv;
#pragma unroll
                for (int j2 = 0; j2 < 8; ++j2) {
                    float hval = bf2f(hp[j2]);
                    int kx = kb * 8 + j2;
                    f32x4 wv = *(const f32x4*)(W1s + kx * 256 + sg * 16);
                    accj[0] += hval * wv[0]; accj[1] += hval * wv[1];
                    accj[2] += hval * wv[2]; accj[3] += hval * wv[3];
                }
            }
            float s4 = accj[0] + accj[1] + accj[2] + accj[3];
            s4 += __shfl_xor(s4, 1); s4 += __shfl_xor(s4, 2);
            s4 += __shfl_xor(s4, 4); s4 += __shfl_xor(s4, 8);
            float mu = s4 * (1.f / 64.f);
            float d0 = accj[0] - mu, d1 = accj[1] - mu, d2 = accj[2] - mu, d3 = accj[3] - mu;
            float v4 = d0 * d0 + d1 * d1 + d2 * d2 + d3 * d3;
            v4 += __shfl_xor(v4, 1); v4 += __shfl_xor(v4, 2);
            v4 += __shfl_xor(v4, 4); v4 += __shfl_xor(v4, 8);
            float rstd = rsqrtf(v4 * (1.f / 64.f) + EPS);
            float dj[4] = {d0, d1, d2, d3};
            float p2 = 0.f;
#pragma unroll
            for (int j = 0; j < 4; ++j) {
                int jj = sg * 4 + j;
                float z = fmaxf(dj[j] * rstd * lg[jj] + lb[jj], 0.f);
                p2 += z * w2[jj];
            }
            p2 += __shfl_xor(p2, 1); p2 += __shfl_xor(p2, 2);
            p2 += __shfl_xor(p2, 4); p2 += __shfl_xor(p2, 8);
            if (sg == 0) out[row0 + rr] = p2 + b2[0];
        }
    }
}

extern "C" void kernel_launch(void* const* d_in, const int* in_sizes, int n_in,
                              void* d_out, int out_size, void* d_ws, size_t ws_size,
                              hipStream_t stream) {
    const float* x    = (const float*)d_in[0];
    const int*   eidx = (const int*)d_in[1];
    const float* ewt  = (const float*)d_in[2];
    const float* efeat= (const float*)d_in[3];
    const float* w_in = (const float*)d_in[4];
    const float* b_in = (const float*)d_in[5];
    const float* lng  = (const float*)d_in[6];
    const float* lnb  = (const float*)d_in[7];
    const float* we1  = (const float*)d_in[8];
    const float* be1  = (const float*)d_in[9];
    const float* we2  = (const float*)d_in[10];
    const float* be2  = (const float*)d_in[11];
    const float* gcnw = (const float*)d_in[12];
    const float* gcnb = (const float*)d_in[13];
    const float* bng  = (const float*)d_in[14];
    const float* bnb  = (const float*)d_in[15];
    const float* wih  = (const float*)d_in[16];
    const float* whh  = (const float*)d_in[17];
    const float* bih  = (const float*)d_in[18];
    const float* bhh  = (const float*)d_in[19];
    const float* wo1  = (const float*)d_in[20];
    const float* bo1  = (const float*)d_in[21];
    const float* lnog = (const float*)d_in[22];
    const float* lnob = (const float*)d_in[23];
    const float* wo2  = (const float*)d_in[24];
    const float* bo2  = (const float*)d_in[25];
    float* out = (float*)d_out;

    // ---- workspace layout (~53MB)
    char* W = (char*)d_ws;
    ushort_t* hA        = (ushort_t*)(W);                        // 4MB  [16][1024][128]
    ushort_t* hB        = (ushort_t*)(W + (4ll << 20));          // 6MB  [23][1024][128]
    ushort_t* y1        = (ushort_t*)(W + (10ll << 20));         // 32MB [16][8192][128]
    ushort_t* hwT       = (ushort_t*)(W + (42ll << 20));         // 4MB  [16][128][1024]
    float*    Adense    = (float*)(W + (46ll << 20));            // 4MB
    ushort_t* Adense_bf = (ushort_t*)(W + (50ll << 20));         // 2MB
    float*    ew        = (float*)(W + (52ll << 20));            // 128KB
    float*    dis       = (float*)(W + (52ll << 20) + 0x20000);  // 4KB
    float*    bsg       = (float*)(W + (52ll << 20) + 0x21000);  // 4KB [2][512]
    ushort_t* gcnwT     = (ushort_t*)(W + (52ll << 20) + 0x22000); // 128KB
    ushort_t* wgi       = (ushort_t*)(W + (52ll << 20) + 0x42000); // 256KB [2][512][128]
    ushort_t* wgh       = (ushort_t*)(W + (52ll << 20) + 0x82000); // 256KB

    const int* srcI = eidx;
    const int* dstI = eidx + 32768;

    // graph preprocessing
    hipMemsetAsync(dis, 0, 1024 * sizeof(float), stream);
    hipMemsetAsync(Adense, 0, 1048576 * sizeof(float), stream);
    edge_att_deg<<<128, 256, 0, stream>>>(efeat, we1, be1, we2, be2, ewt, dstI, ew, dis);
    make_dis<<<4, 256, 0, stream>>>(dis);
    scatterA<<<128, 256, 0, stream>>>(srcI, dstI, ew, dis, Adense);
    convF2B<<<4096, 256, 0, stream>>>(Adense, Adense_bf, 1048576);
    conv_all<<<772, 256, 0, stream>>>(gcnw, wih, whh, bih, bhh, gcnwT, wgi, wgh, bsg);

    // input projection -> compact hA/hB (wave-per-row, barrier-free)
    in_proj_ln<<<5888, 256, 0, stream>>>(x, w_in, b_in, lng, lnb, hA, hB);

    // GCN layers: feat GEMM (-> hwT), then merged adjacency+combine
    for (int l = 0; l < 4; ++l) {
        gemm_feat_t<<<dim3(8, 16, 1), 256, 0, stream>>>(hA, gcnwT + l * 16384, hwT);
        gcn_layer<<<624, 256, 0, stream>>>(hA, hB, gcnwT + l * 16384, Adense_bf, hwT,
                                           dis, gcnb + l * 128, bng + l * 128, bnb + l * 128);
    }

    // LSTM: layer 1 gathers from compact hA/hB; layer 2 reads y1 and fuses the head
    lstm_layer<0><<<128, 512, 0, stream>>>(hA, hB, nullptr, wgi, wgh, bsg, y1,
                                           nullptr, nullptr, nullptr, nullptr,
                                           nullptr, nullptr, nullptr);
    lstm_layer<1><<<128, 512, 0, stream>>>(nullptr, nullptr, y1,
                                           wgi + 65536, wgh + 65536, bsg + 512, nullptr,
                                           wo1, bo1, lnog, lnob, wo2, bo2, out);
}

// Round 19
// 247.414 us; speedup vs baseline: 1.4976x; 1.4976x over previous
//
#include <hip/hip_runtime.h>
#include <cstdint>

// B=8, S=16, N=1024, F=16, H=128, E=32768, L=4, BN=8192
#define EPS 1e-5f

typedef unsigned short ushort_t;
typedef __bf16 bf16x8 __attribute__((ext_vector_type(8)));
typedef float f32x4 __attribute__((ext_vector_type(4)));

#define GLD16(gp, lp) __builtin_amdgcn_global_load_lds( \
    (const __attribute__((address_space(1))) void*)(gp), \
    (__attribute__((address_space(3))) void*)(lp), 16, 0, 0)

__device__ __forceinline__ float sigm(float x) { return 1.f / (1.f + expf(-x)); }
__device__ __forceinline__ unsigned short f2bf(float f) {
    unsigned int u = __builtin_bit_cast(unsigned int, f);
    return (unsigned short)((u + 0x7fffu + ((u >> 16) & 1u)) >> 16);
}
__device__ __forceinline__ float bf2f(unsigned short s) {
    unsigned int u = ((unsigned int)s) << 16;
    return __builtin_bit_cast(float, u);
}
__device__ __forceinline__ float sigm_fast(float x) {
    float t = __builtin_amdgcn_exp2f(-1.44269504f * x);
    return __builtin_amdgcn_rcpf(1.f + t);
}
__device__ __forceinline__ float tanh_fast(float x) {
    float xc = fminf(fmaxf(x, -15.f), 15.f);
    float t = __builtin_amdgcn_exp2f(-2.88539008f * xc);
    return (1.f - t) * __builtin_amdgcn_rcpf(1.f + t);
}

// ---------------- edge attention + degree accumulate
__global__ __launch_bounds__(256) void edge_att_deg(const float* __restrict__ ef,
                                                    const float* __restrict__ we1,
                                                    const float* __restrict__ be1,
                                                    const float* __restrict__ we2,
                                                    const float* __restrict__ be2,
                                                    const float* __restrict__ ewin,
                                                    const int* __restrict__ dst,
                                                    float* __restrict__ ew,
                                                    float* __restrict__ deg) {
    int e = blockIdx.x * blockDim.x + threadIdx.x;
    if (e >= 32768) return;
    float x = ef[e];
    float acc = 0.f;
    for (int h = 0; h < 128; ++h) {
        float v = fmaxf(x * we1[h] + be1[h], 0.f);
        acc += v * we2[h];
    }
    float wv = ewin[e] * sigm(acc + be2[0]);
    ew[e] = wv;
    atomicAdd(&deg[dst[e]], wv);
}
__global__ __launch_bounds__(256) void make_dis(float* __restrict__ deg) {
    int i = blockIdx.x * blockDim.x + threadIdx.x;
    if (i < 1024) { float d = deg[i] + 1.0f; deg[i] = (d > 0.f) ? rsqrtf(d) : 0.f; }
}
__global__ __launch_bounds__(256) void scatterA(const int* __restrict__ src,
                                                const int* __restrict__ dst,
                                                const float* __restrict__ ew,
                                                const float* __restrict__ dis,
                                                float* __restrict__ A) {
    int e = blockIdx.x * blockDim.x + threadIdx.x;
    if (e >= 32768) return;
    int s = src[e], d = dst[e];
    atomicAdd(&A[d * 1024 + s], dis[s] * ew[e] * dis[d]);
}

// ---------------- converters
__global__ __launch_bounds__(256) void convF2B(const float* __restrict__ s,
                                               ushort_t* __restrict__ d, int n) {
    int i = blockIdx.x * blockDim.x + threadIdx.x;
    if (i < n) d[i] = f2bf(s[i]);
}
// merged conversions (64-col gate layout: col' = (h>>4)*64 + gate*16 + (h&15))
__global__ __launch_bounds__(256) void conv_all(const float* __restrict__ gcnw,
                                                const float* __restrict__ wih,
                                                const float* __restrict__ whh,
                                                const float* __restrict__ bih,
                                                const float* __restrict__ bhh,
                                                ushort_t* __restrict__ gcnwT,
                                                ushort_t* __restrict__ wgi,
                                                ushort_t* __restrict__ wgh,
                                                float* __restrict__ bsg) {
    int i = blockIdx.x * 256 + threadIdx.x;
    if (i < 65536) {                       // gcnw [l][in][out] -> [l][out][in] bf16
        int l = i >> 14, rem = i & 16383, in = rem >> 7, outc = rem & 127;
        gcnwT[l * 16384 + outc * 128 + in] = f2bf(gcnw[i]);
        return;
    }
    int j = i - 65536;
    if (j < 131072) {
        int l = j >> 16, rem = j & 65535, c = rem >> 7, kx = rem & 127;
        int g = (c >> 4) & 3, h = (c >> 6) * 16 + (c & 15);
        int src = (l * 512 + g * 128 + h) * 128 + kx;
        wgi[j] = f2bf(wih[src]);
        wgh[j] = f2bf(whh[src]);
        return;
    }
    int b = j - 131072;
    if (b < 1024) {
        int l = b >> 9, c = b & 511;
        int g = (c >> 4) & 3, h = (c >> 6) * 16 + (c & 15);
        int src = l * 512 + g * 128 + h;
        bsg[b] = bih[src] + bhh[src];
    }
}

// ---------------- input projection + LN + ReLU, wave-per-row (barrier-free)
__global__ __launch_bounds__(256) void in_proj_ln(const float* __restrict__ x,
                                                  const float* __restrict__ w,
                                                  const float* __restrict__ bias,
                                                  const float* __restrict__ g,
                                                  const float* __restrict__ be,
                                                  ushort_t* __restrict__ hA,
                                                  ushort_t* __restrict__ hB) {
    int row = blockIdx.x * 4 + (threadIdx.x >> 6);   // < 23552
    int lane = threadIdx.x & 63;
    int k = row >> 10, n = row & 1023;
    float xv = x[(int64_t)row * 16 + (lane & 15)];
    float a0 = bias[lane], a1 = bias[lane + 64];
#pragma unroll
    for (int f = 0; f < 16; ++f) {
        float xf = __shfl(xv, f, 16);
        a0 += xf * w[f * 128 + lane];
        a1 += xf * w[f * 128 + lane + 64];
    }
    float s = a0 + a1;
#pragma unroll
    for (int off = 1; off < 64; off <<= 1) s += __shfl_xor(s, off, 64);
    float mu = s * (1.f / 128.f);
    float d0 = a0 - mu, d1 = a1 - mu;
    float vs = d0 * d0 + d1 * d1;
#pragma unroll
    for (int off = 1; off < 64; off <<= 1) vs += __shfl_xor(vs, off, 64);
    float rstd = rsqrtf(vs * (1.f / 128.f) + EPS);
    float v0 = fmaxf(d0 * rstd * g[lane] + be[lane], 0.f);
    float v1 = fmaxf(d1 * rstd * g[lane + 64] + be[lane + 64], 0.f);
    int64_t idx = ((int64_t)k * 1024 + n) * 128 + lane;
    ushort_t b0 = f2bf(v0), b1v = f2bf(v1);
    if (k < 16) { hA[idx] = b0; hA[idx + 64] = b1v; }
    hB[idx] = b0; hB[idx + 64] = b1v;
}

// ---------------- feature GEMM from hA, transposed output hwT[t][col][bn]
__global__ __launch_bounds__(256) void gemm_feat_t(const ushort_t* __restrict__ hA,
                                                   const ushort_t* __restrict__ Wt,
                                                   ushort_t* __restrict__ hwT) {
    __shared__ __align__(16) char AsB[32768];
    __shared__ __align__(16) char BsB[32768];
    const int tid = threadIdx.x, lane = tid & 63, wid = tid >> 6;
    const int wr = wid >> 1, wc = wid & 1, q = lane >> 4, l15 = lane & 15;
    const int t = blockIdx.y;
    const int row0 = blockIdx.x * 128;
    const ushort_t* Ap = hA + ((int64_t)t * 1024 + row0) * 128;
    f32x4 acc[4][4];
#pragma unroll
    for (int m = 0; m < 4; ++m)
#pragma unroll
        for (int n = 0; n < 4; ++n) acc[m][n] = f32x4{0.f, 0.f, 0.f, 0.f};
#pragma unroll
    for (int i = 0; i < 8; ++i) {
        int id = i * 256 + tid; int r = id >> 4, sg = id & 15;
        uint4 va = *(const uint4*)(Ap + r * 128 + sg * 8);
        *(uint4*)(AsB + r * 256 + ((sg * 16) ^ ((r & 7) << 4))) = va;
        uint4 vb = *(const uint4*)(Wt + r * 128 + sg * 8);
        *(uint4*)(BsB + r * 256 + ((sg * 16) ^ ((r & 7) << 4))) = vb;
    }
    __syncthreads();
#pragma unroll
    for (int kk = 0; kk < 4; ++kk) {
        bf16x8 af[4], bfr[4];
#pragma unroll
        for (int m = 0; m < 4; ++m) {
            int row = wr * 64 + m * 16 + l15;
            af[m] = __builtin_bit_cast(bf16x8,
                *(const uint4*)(AsB + row * 256 + ((kk * 64 + q * 16) ^ ((row & 7) << 4))));
        }
#pragma unroll
        for (int n = 0; n < 4; ++n) {
            int col = wc * 64 + n * 16 + l15;
            bfr[n] = __builtin_bit_cast(bf16x8,
                *(const uint4*)(BsB + col * 256 + ((kk * 64 + q * 16) ^ ((col & 7) << 4))));
        }
#pragma unroll
        for (int m = 0; m < 4; ++m)
#pragma unroll
            for (int n = 0; n < 4; ++n)
                acc[m][n] = __builtin_amdgcn_mfma_f32_16x16x32_bf16(af[m], bfr[n], acc[m][n], 0, 0, 0);
    }
#pragma unroll
    for (int m = 0; m < 4; ++m) {
        int bn = row0 + wr * 64 + m * 16 + q * 4;
#pragma unroll
        for (int n = 0; n < 4; ++n) {
            int col = wc * 64 + n * 16 + l15;
            ushort4 u;
            u.x = f2bf(acc[m][n][0]); u.y = f2bf(acc[m][n][1]);
            u.z = f2bf(acc[m][n][2]); u.w = f2bf(acc[m][n][3]);
            *(ushort4*)(hwT + ((int64_t)t * 128 + col) * 1024 + bn) = u;
        }
    }
}

// ---------------- merged GCN layer: feat GEMM + adjacency GEMM in registers + combine.
__global__ __launch_bounds__(256) void gcn_layer(ushort_t* __restrict__ hA,
                                                 ushort_t* __restrict__ hB,
                                                 const ushort_t* __restrict__ Wt,
                                                 const ushort_t* __restrict__ Abf,
                                                 const ushort_t* __restrict__ hwT,
                                                 const float* __restrict__ dis,
                                                 const float* __restrict__ gcnb,
                                                 const float* __restrict__ bng,
                                                 const float* __restrict__ bnb) {
    __shared__ __align__(16) char AsB[16384];
    __shared__ __align__(16) char BsB[32768];
    const int tid = threadIdx.x, lane = tid & 63, wid = tid >> 6;
    const int wr = wid >> 1, wc = wid & 1, q = lane >> 4, l15 = lane & 15;
    const int bx = blockIdx.x;
    const bool adj = bx < 256;
    const int lb = adj ? bx : bx - 256;
    const int tt = lb >> 4;
    const int n0 = (lb & 15) * 64;
    ushort_t* Ap = (adj ? hA : hB) + ((int64_t)tt * 1024 + n0) * 128;

#pragma unroll
    for (int i = 0; i < 4; ++i) {
        int id = i * 256 + tid; int r = id >> 4, sg = id & 15;
        uint4 va = *(const uint4*)(Ap + r * 128 + sg * 8);
        *(uint4*)(AsB + r * 256 + ((sg * 16) ^ ((r & 7) << 4))) = va;
    }
#pragma unroll
    for (int i = 0; i < 8; ++i) {
        int id = i * 256 + tid; int r = id >> 4, sg = id & 15;
        uint4 vb = *(const uint4*)(Wt + r * 128 + sg * 8);
        *(uint4*)(BsB + r * 256 + ((sg * 16) ^ ((r & 7) << 4))) = vb;
    }
    __syncthreads();

    f32x4 accF[2][4];
#pragma unroll
    for (int m = 0; m < 2; ++m)
#pragma unroll
        for (int n = 0; n < 4; ++n) accF[m][n] = f32x4{0.f, 0.f, 0.f, 0.f};
#pragma unroll
    for (int kk = 0; kk < 4; ++kk) {
        bf16x8 af[2], bfr[4];
#pragma unroll
        for (int m = 0; m < 2; ++m) {
            int row = wr * 32 + m * 16 + l15;
            af[m] = __builtin_bit_cast(bf16x8,
                *(const uint4*)(AsB + row * 256 + ((kk * 64 + q * 16) ^ ((row & 7) << 4))));
        }
#pragma unroll
        for (int n = 0; n < 4; ++n) {
            int col = wc * 64 + n * 16 + l15;
            bfr[n] = __builtin_bit_cast(bf16x8,
                *(const uint4*)(BsB + col * 256 + ((kk * 64 + q * 16) ^ ((col & 7) << 4))));
        }
#pragma unroll
        for (int m = 0; m < 2; ++m)
#pragma unroll
            for (int n = 0; n < 4; ++n)
                accF[m][n] = __builtin_amdgcn_mfma_f32_16x16x32_bf16(af[m], bfr[n], accF[m][n], 0, 0, 0);
    }

    f32x4 accA[2][4];
#pragma unroll
    for (int m = 0; m < 2; ++m)
#pragma unroll
        for (int n = 0; n < 4; ++n) accA[m][n] = f32x4{0.f, 0.f, 0.f, 0.f};
    if (adj) {
        const int rl8 = lane >> 3;
        const int sgg = (lane & 7) ^ rl8;
        for (int k0 = 0; k0 < 1024; k0 += 64) {
            __syncthreads();
#pragma unroll
            for (int i = 0; i < 2; ++i) {
                int r = i * 32 + wid * 8 + rl8;
                GLD16(Abf + (int64_t)(n0 + r) * 1024 + k0 + sgg * 8,
                      BsB + (i * 32 + wid * 8) * 128);
            }
#pragma unroll
            for (int i = 0; i < 4; ++i) {
                int r = i * 32 + wid * 8 + rl8;
                GLD16(hwT + (int64_t)tt * 131072 + (int64_t)r * 1024 + k0 + sgg * 8,
                      BsB + 8192 + (i * 32 + wid * 8) * 128);
            }
            __syncthreads();
#pragma unroll
            for (int kk = 0; kk < 2; ++kk) {
                bf16x8 af2[2], bf2[4];
#pragma unroll
                for (int m = 0; m < 2; ++m) {
                    int row = wr * 32 + m * 16 + l15;
                    af2[m] = __builtin_bit_cast(bf16x8,
                        *(const uint4*)(BsB + row * 128 + ((kk * 64 + q * 16) ^ ((row & 7) << 4))));
                }
#pragma unroll
                for (int n = 0; n < 4; ++n) {
                    int col = wc * 64 + n * 16 + l15;
                    bf2[n] = __builtin_bit_cast(bf16x8,
                        *(const uint4*)(BsB + 8192 + col * 128 + ((kk * 64 + q * 16) ^ ((col & 7) << 4))));
                }
#pragma unroll
                for (int m = 0; m < 2; ++m)
#pragma unroll
                    for (int n = 0; n < 4; ++n)
                        accA[m][n] = __builtin_amdgcn_mfma_f32_16x16x32_bf16(af2[m], bf2[n], accA[m][n], 0, 0, 0);
            }
        }
    }
    __syncthreads();

    const float rs = rsqrtf(1.f + EPS);
#pragma unroll
    for (int n = 0; n < 4; ++n) {
        int col = wc * 64 + n * 16 + l15;
        float gb = gcnb[col], sc = bng[col] * rs, bb = bnb[col];
        int seg16 = (col >> 3) * 16, wb = (col & 7) * 2;
#pragma unroll
        for (int m = 0; m < 2; ++m) {
            int rl0 = wr * 32 + m * 16 + q * 4;
#pragma unroll
            for (int e = 0; e < 4; ++e) {
                int rl = rl0 + e;
                float sl = 1.f, ad = 0.f;
                if (adj) { float dv = dis[n0 + rl]; sl = dv * dv; ad = accA[m][n][e]; }
                float mv = sl * accF[m][n][e] + gb + ad;
                ushort_t rbv = *(const ushort_t*)(AsB + rl * 256 + (seg16 ^ ((rl & 7) << 4)) + wb);
                float v = fmaxf(mv * sc + bb, 0.f) + bf2f(rbv);
                *(ushort_t*)(BsB + rl * 256 + (seg16 ^ ((rl & 7) << 4)) + wb) = f2bf(v);
            }
        }
    }
    __syncthreads();
#pragma unroll
    for (int i = 0; i < 4; ++i) {
        int id = i * 256 + tid; int r = id >> 4, sg = id & 15;
        uint4 v = *(const uint4*)(BsB + r * 256 + ((sg * 16) ^ ((r & 7) << 4)));
        *(uint4*)(Ap + r * 128 + sg * 8) = v;
    }
}

// ---------------- LSTM layer: round-7 structure, ONE barrier/step via
// Xs[2]+Hs[2] ping-pong. Best-measured LSTM decomposition (round 13).
template <int MODE>
__global__ __launch_bounds__(512, 2) void lstm_layer(
    const ushort_t* __restrict__ hA, const ushort_t* __restrict__ hB,
    const ushort_t* __restrict__ X,
    const ushort_t* __restrict__ Wi, const ushort_t* __restrict__ Wh,
    const float* __restrict__ bs,
    ushort_t* __restrict__ Y,
    const float* __restrict__ w1, const float* __restrict__ b1,
    const float* __restrict__ lg, const float* __restrict__ lb,
    const float* __restrict__ w2, const float* __restrict__ b2,
    float* __restrict__ out) {
    __shared__ __align__(16) char Xs[16384];   // 2 slots
    __shared__ __align__(16) char Hs[16384];   // 2 slots
    __shared__ __align__(16) char W1s[32768];
    const int tid = threadIdx.x, lane = tid & 63, w = tid >> 6;
    const int q = lane >> 4, l15 = lane & 15;
    const int row0 = blockIdx.x * 32;
    const int r = tid >> 4, sg = tid & 15;
    const int bb = row0 >> 10, n0 = row0 & 1023;

    *(uint4*)(Hs + tid * 16) = uint4{0, 0, 0, 0};   // zero slot 0
    if constexpr (MODE == 1) {
#pragma unroll
        for (int i = 0; i < 4; ++i)
            *(uint4*)(W1s + (i * 512 + tid) * 16) =
                *(const uint4*)((const char*)w1 + (i * 512 + tid) * 16);
    }
    bf16x8 wi[4][4], wh[4][4];
#pragma unroll
    for (int n = 0; n < 4; ++n)
#pragma unroll
        for (int kk = 0; kk < 4; ++kk) {
            int col = w * 64 + n * 16 + l15;
            wi[n][kk] = __builtin_bit_cast(bf16x8, *(const uint4*)(Wi + col * 128 + kk * 32 + q * 8));
            wh[n][kk] = __builtin_bit_cast(bf16x8, *(const uint4*)(Wh + col * 128 + kk * 32 + q * 8));
        }
    const int cb = w * 64 + l15;
    const float bi = bs[cb], bf = bs[cb + 16], bg = bs[cb + 32], bo = bs[cb + 48];
    const int k = w * 16 + l15;
    float c[2][4] = {};

    auto xsrc = [&](int t) -> const ushort_t* {
        if constexpr (MODE == 0)
            return (bb == 0) ? hA + ((int64_t)t * 1024 + n0) * 128
                             : hB + ((int64_t)(t + bb) * 1024 + n0) * 128;
        else
            return X + ((int64_t)t * 8192 + row0) * 128;
    };

    {
        uint4 x0 = *(const uint4*)(xsrc(0) + r * 128 + sg * 8);
        *(uint4*)(Xs + r * 256 + ((sg * 16) ^ ((r & 7) << 4))) = x0;   // slot 0
    }
    __syncthreads();

    for (int t = 0; t < 16; ++t) {
        const int p = (t & 1) * 8192, pn = ((t + 1) & 1) * 8192;
        uint4 xn;
        if (t < 15) xn = *(const uint4*)(xsrc(t + 1) + r * 128 + sg * 8);

        f32x4 acc[2][4];
#pragma unroll
        for (int m = 0; m < 2; ++m)
#pragma unroll
            for (int n = 0; n < 4; ++n) acc[m][n] = f32x4{0.f, 0.f, 0.f, 0.f};
#pragma unroll
        for (int kk = 0; kk < 4; ++kk) {
            bf16x8 ax[2], ah[2];
#pragma unroll
            for (int m = 0; m < 2; ++m) {
                int rw = m * 16 + l15;
                int off = rw * 256 + ((kk * 64 + q * 16) ^ ((rw & 7) << 4));
                ax[m] = __builtin_bit_cast(bf16x8, *(const uint4*)(Xs + p + off));
                ah[m] = __builtin_bit_cast(bf16x8, *(const uint4*)(Hs + p + off));
            }
#pragma unroll
            for (int n = 0; n < 4; ++n)
#pragma unroll
                for (int m = 0; m < 2; ++m) {
                    acc[m][n] = __builtin_amdgcn_mfma_f32_16x16x32_bf16(ax[m], wi[n][kk], acc[m][n], 0, 0, 0);
                    acc[m][n] = __builtin_amdgcn_mfma_f32_16x16x32_bf16(ah[m], wh[n][kk], acc[m][n], 0, 0, 0);
                }
        }
        // cell -> write h to OTHER slot (no WAR with current-step readers)
#pragma unroll
        for (int m = 0; m < 2; ++m)
#pragma unroll
            for (int e = 0; e < 4; ++e) {
                float ig = sigm_fast(acc[m][0][e] + bi);
                float fg = sigm_fast(acc[m][1][e] + bf);
                float gg = tanh_fast(acc[m][2][e] + bg);
                float og = sigm_fast(acc[m][3][e] + bo);
                float cn = fg * c[m][e] + ig * gg;
                c[m][e] = cn;
                float hn = og * tanh_fast(cn);
                int rw = m * 16 + q * 4 + e;
                int byte = rw * 256 + ((((k >> 3) * 16) ^ ((rw & 7) << 4)) | ((k & 7) * 2));
                *(ushort_t*)(Hs + pn + byte) = f2bf(hn);
            }
        if (t < 15)
            *(uint4*)(Xs + pn + r * 256 + ((sg * 16) ^ ((r & 7) << 4))) = xn;
        __syncthreads();   // single barrier: slot t+1 (X and H) now complete

        if constexpr (MODE == 0) {
            uint4 v = *(const uint4*)(Hs + pn + r * 256 + ((sg * 16) ^ ((r & 7) << 4)));
            *(uint4*)(Y + ((int64_t)t * 8192 + row0 + r) * 128 + sg * 8) = v;
        }
    }

    if constexpr (MODE == 1) {
        // final h2 in Hs slot 0 (after t=15, pn=0)
        float accj[4] = {b1[sg * 4 + 0], b1[sg * 4 + 1], b1[sg * 4 + 2], b1[sg * 4 + 3]};
#pragma unroll
        for (int kb = 0; kb < 16; ++kb) {
            uint4 hv = *(const uint4*)(Hs + r * 256 + ((kb * 16) ^ ((r & 7) << 4)));
            const ushort_t* hp = (const ushort_t*)&hv;
#pragma unroll
            for (int j2 = 0; j2 < 8; ++j2) {
                float hval = bf2f(hp[j2]);
                int kx = kb * 8 + j2;
                f32x4 wv = *(const f32x4*)(W1s + kx * 256 + sg * 16);
                accj[0] += hval * wv[0]; accj[1] += hval * wv[1];
                accj[2] += hval * wv[2]; accj[3] += hval * wv[3];
            }
        }
        float s4 = accj[0] + accj[1] + accj[2] + accj[3];
        s4 += __shfl_xor(s4, 1); s4 += __shfl_xor(s4, 2);
        s4 += __shfl_xor(s4, 4); s4 += __shfl_xor(s4, 8);
        float mu = s4 * (1.f / 64.f);
        float d0 = accj[0] - mu, d1 = accj[1] - mu, d2 = accj[2] - mu, d3 = accj[3] - mu;
        float v4 = d0 * d0 + d1 * d1 + d2 * d2 + d3 * d3;
        v4 += __shfl_xor(v4, 1); v4 += __shfl_xor(v4, 2);
        v4 += __shfl_xor(v4, 4); v4 += __shfl_xor(v4, 8);
        float rstd = rsqrtf(v4 * (1.f / 64.f) + EPS);
        float dj[4] = {d0, d1, d2, d3};
        float p2 = 0.f;
#pragma unroll
        for (int j = 0; j < 4; ++j) {
            int jj = sg * 4 + j;
            float z = fmaxf(dj[j] * rstd * lg[jj] + lb[jj], 0.f);
            p2 += z * w2[jj];
        }
        p2 += __shfl_xor(p2, 1); p2 += __shfl_xor(p2, 2);
        p2 += __shfl_xor(p2, 4); p2 += __shfl_xor(p2, 8);
        if (sg == 0) out[row0 + r] = p2 + b2[0];
    }
}

extern "C" void kernel_launch(void* const* d_in, const int* in_sizes, int n_in,
                              void* d_out, int out_size, void* d_ws, size_t ws_size,
                              hipStream_t stream) {
    const float* x    = (const float*)d_in[0];
    const int*   eidx = (const int*)d_in[1];
    const float* ewt  = (const float*)d_in[2];
    const float* efeat= (const float*)d_in[3];
    const float* w_in = (const float*)d_in[4];
    const float* b_in = (const float*)d_in[5];
    const float* lng  = (const float*)d_in[6];
    const float* lnb  = (const float*)d_in[7];
    const float* we1  = (const float*)d_in[8];
    const float* be1  = (const float*)d_in[9];
    const float* we2  = (const float*)d_in[10];
    const float* be2  = (const float*)d_in[11];
    const float* gcnw = (const float*)d_in[12];
    const float* gcnb = (const float*)d_in[13];
    const float* bng  = (const float*)d_in[14];
    const float* bnb  = (const float*)d_in[15];
    const float* wih  = (const float*)d_in[16];
    const float* whh  = (const float*)d_in[17];
    const float* bih  = (const float*)d_in[18];
    const float* bhh  = (const float*)d_in[19];
    const float* wo1  = (const float*)d_in[20];
    const float* bo1  = (const float*)d_in[21];
    const float* lnog = (const float*)d_in[22];
    const float* lnob = (const float*)d_in[23];
    const float* wo2  = (const float*)d_in[24];
    const float* bo2  = (const float*)d_in[25];
    float* out = (float*)d_out;

    // ---- workspace layout (~53MB)
    char* W = (char*)d_ws;
    ushort_t* hA        = (ushort_t*)(W);                        // 4MB  [16][1024][128]
    ushort_t* hB        = (ushort_t*)(W + (4ll << 20));          // 6MB  [23][1024][128]
    ushort_t* y1        = (ushort_t*)(W + (10ll << 20));         // 32MB [16][8192][128]
    ushort_t* hwT       = (ushort_t*)(W + (42ll << 20));         // 4MB  [16][128][1024]
    float*    Adense    = (float*)(W + (46ll << 20));            // 4MB
    ushort_t* Adense_bf = (ushort_t*)(W + (50ll << 20));         // 2MB
    float*    ew        = (float*)(W + (52ll << 20));            // 128KB
    float*    dis       = (float*)(W + (52ll << 20) + 0x20000);  // 4KB
    float*    bsg       = (float*)(W + (52ll << 20) + 0x21000);  // 4KB [2][512]
    ushort_t* gcnwT     = (ushort_t*)(W + (52ll << 20) + 0x22000); // 128KB
    ushort_t* wgi       = (ushort_t*)(W + (52ll << 20) + 0x42000); // 256KB [2][512][128]
    ushort_t* wgh       = (ushort_t*)(W + (52ll << 20) + 0x82000); // 256KB

    const int* srcI = eidx;
    const int* dstI = eidx + 32768;

    // graph preprocessing
    hipMemsetAsync(dis, 0, 1024 * sizeof(float), stream);
    hipMemsetAsync(Adense, 0, 1048576 * sizeof(float), stream);
    edge_att_deg<<<128, 256, 0, stream>>>(efeat, we1, be1, we2, be2, ewt, dstI, ew, dis);
    make_dis<<<4, 256, 0, stream>>>(dis);
    scatterA<<<128, 256, 0, stream>>>(srcI, dstI, ew, dis, Adense);
    convF2B<<<4096, 256, 0, stream>>>(Adense, Adense_bf, 1048576);
    conv_all<<<772, 256, 0, stream>>>(gcnw, wih, whh, bih, bhh, gcnwT, wgi, wgh, bsg);

    // input projection -> compact hA/hB (wave-per-row, barrier-free)
    in_proj_ln<<<5888, 256, 0, stream>>>(x, w_in, b_in, lng, lnb, hA, hB);

    // GCN layers: feat GEMM (-> hwT), then merged adjacency+combine
    for (int l = 0; l < 4; ++l) {
        gemm_feat_t<<<dim3(8, 16, 1), 256, 0, stream>>>(hA, gcnwT + l * 16384, hwT);
        gcn_layer<<<624, 256, 0, stream>>>(hA, hB, gcnwT + l * 16384, Adense_bf, hwT,
                                           dis, gcnb + l * 128, bng + l * 128, bnb + l * 128);
    }

    // LSTM: layer 1 gathers from compact hA/hB; layer 2 reads y1 and fuses the head
    lstm_layer<0><<<256, 512, 0, stream>>>(hA, hB, nullptr, wgi, wgh, bsg, y1,
                                           nullptr, nullptr, nullptr, nullptr,
                                           nullptr, nullptr, nullptr);
    lstm_layer<1><<<256, 512, 0, stream>>>(nullptr, nullptr, y1,
                                           wgi + 65536, wgh + 65536, bsg + 512, nullptr,
                                           wo1, bo1, lnog, lnob, wo2, bo2, out);
}